// Round 2
// baseline (246.505 us; speedup 1.0000x reference)
//
#include <hip/hip_runtime.h>
#include <math.h>

#define B_SZ 4096
#define N_PTS 2048
#define BLOCK 256
#define WPB (BLOCK / 64)          // waves per block = 4
#define GRID (B_SZ / WPB)         // 1024 blocks

__device__ __forceinline__ float huber1(float a) {
    // a >= 0, delta = 1: 0.5*q*q + (a - q), q = min(a,1)
    float q = fminf(a, 1.0f);
    return 0.5f * q * q + (a - q);
}

__global__ __launch_bounds__(BLOCK) void loss_kernel(
    const float* __restrict__ mask_xyz_mean,    // (B,3)
    const float* __restrict__ point_cloud,      // (B,3,N)
    const float* __restrict__ x_delta,          // (B,3,N)
    const float* __restrict__ center_label,     // (B,3)
    const float* __restrict__ size_residual,    // (B,3)
    const float* __restrict__ heading_residual, // (B,)
    const float* __restrict__ mean_sizes,       // (8,3)
    const int*   __restrict__ size_class,       // (B,)
    const int*   __restrict__ heading_class,    // (B,)
    float* __restrict__ out)
{
    const int wave = threadIdx.x >> 6;
    const int lane = threadIdx.x & 63;
    const int b    = blockIdx.x * WPB + wave;   // one wave per batch element

    // Wave-uniform scalars (same-address broadcast loads)
    const float cx = center_label[b * 3 + 0];
    const float cy = center_label[b * 3 + 1];

    const float vnorm2 = cx * cx + cy * cy;
    const float vnorm  = sqrtf(vnorm2);
    const float pdx = -cy / vnorm;
    const float pdy =  cx / vnorm;

    const size_t base = (size_t)b * 3 * N_PTS;
    const float4* px4 = (const float4*)(point_cloud + base);            // row 0 (x)
    const float4* py4 = (const float4*)(point_cloud + base + N_PTS);    // row 1 (y)
    const float4* pd4 = (const float4*)(x_delta + base);                // 3*N contiguous

    float s_pp = 0.f, s_pp2 = 0.f, s_t = 0.f, s_t2 = 0.f, s_d2 = 0.f;

    // pc rows 0/1: 512 float4 each -> 8 per lane per row
    #pragma unroll
    for (int k = 0; k < N_PTS / 4 / 64; ++k) {
        const int i = lane + k * 64;
        const float4 x4 = px4[i];
        const float4 y4 = py4[i];
        {
            float pp = x4.x * pdx + y4.x * pdy;
            float t  = x4.x * cx  + y4.x * cy;
            s_pp += pp; s_pp2 += pp * pp; s_t += t; s_t2 += t * t;
        }
        {
            float pp = x4.y * pdx + y4.y * pdy;
            float t  = x4.y * cx  + y4.y * cy;
            s_pp += pp; s_pp2 += pp * pp; s_t += t; s_t2 += t * t;
        }
        {
            float pp = x4.z * pdx + y4.z * pdy;
            float t  = x4.z * cx  + y4.z * cy;
            s_pp += pp; s_pp2 += pp * pp; s_t += t; s_t2 += t * t;
        }
        {
            float pp = x4.w * pdx + y4.w * pdy;
            float t  = x4.w * cx  + y4.w * cy;
            s_pp += pp; s_pp2 += pp * pp; s_t += t; s_t2 += t * t;
        }
    }

    // x_delta: 1536 float4 -> 24 per lane
    #pragma unroll 8
    for (int k = 0; k < 3 * N_PTS / 4 / 64; ++k) {
        const int i = lane + k * 64;
        const float4 d = pd4[i];
        s_d2 += d.x * d.x + d.y * d.y + d.z * d.z + d.w * d.w;
    }

    // wave(64) shuffle reduction — no LDS, no __syncthreads
    #pragma unroll
    for (int off = 32; off > 0; off >>= 1) {
        s_pp  += __shfl_down(s_pp,  off, 64);
        s_pp2 += __shfl_down(s_pp2, off, 64);
        s_t   += __shfl_down(s_t,   off, 64);
        s_t2  += __shfl_down(s_t2,  off, 64);
        s_d2  += __shfl_down(s_d2,  off, 64);
    }

    if (lane == 0) {
        // --- label-side scalar math ---
        const float mx = mask_xyz_mean[b * 3 + 0];
        const float my = mask_xyz_mean[b * 3 + 1];
        const float mz = mask_xyz_mean[b * 3 + 2];
        const float cz = center_label[b * 3 + 2];
        const float dxc = mx - cx, dyc = my - cy, dzc = mz - cz;
        const float center_dist = sqrtf(dxc * dxc + dyc * dyc + dzc * dzc);

        const int sc = size_class[b];
        const float l  = mean_sizes[sc * 3 + 0] + size_residual[b * 3 + 0];
        const float w_ = mean_sizes[sc * 3 + 1] + size_residual[b * 3 + 1];
        // h (size z) does not affect the 2D corners used below

        const float theta = heading_residual[b] +
                            (float)heading_class[b] * (float)(M_PI / 12.0);
        const float c = cosf(theta);
        const float s = sinf(theta);
        const float hl = 0.5f * l, hw = 0.5f * w_;

        // bottom corners k=4..7: sx={1,1,-1,-1}, sy={1,-1,-1,1}
        float X[4], Y[4];
        X[0] =  c * hl - s * hw + cx;  Y[0] =  s * hl + c * hw + cy;
        X[1] =  c * hl + s * hw + cx;  Y[1] =  s * hl - c * hw + cy;
        X[2] = -c * hl + s * hw + cx;  Y[2] = -s * hl - c * hw + cy;
        X[3] = -c * hl - s * hw + cx;  Y[3] = -s * hl + c * hw + cy;

        float ppmax = -INFINITY, ppmin = INFINITY;
        float pmax  = -INFINITY, pmin  = INFINITY;
        #pragma unroll
        for (int k = 0; k < 4; ++k) {
            const float pp = X[k] * pdx + Y[k] * pdy;
            const float pj = (X[k] * cx + Y[k] * cy) / vnorm;
            ppmax = fmaxf(ppmax, pp); ppmin = fminf(ppmin, pp);
            pmax  = fmaxf(pmax,  pj); pmin  = fminf(pmin,  pj);
        }
        const float std_y_label  = (ppmax - ppmin) * 0.25f;
        const float mean_y_label = (ppmax + ppmin) * 0.5f;
        const float std_label    = (pmax - pmin) * 0.25f;
        const float mean_label   = (pmax + pmin) * 0.5f;

        // --- point-cloud stats (ddof=1) ---
        const float invN   = 1.0f / (float)N_PTS;
        const float invNm1 = 1.0f / (float)(N_PTS - 1);

        const float mean_y_pc = s_pp * invN;
        const float var_y = (s_pp2 - s_pp * s_pp * invN) * invNm1;
        const float std_y_pc = sqrtf(fmaxf(var_y, 0.0f));

        const float mean_pc = (s_t * invN) / vnorm;
        const float var_x = ((s_t2 - s_t * s_t * invN) * invNm1) / vnorm2;
        const float std_pc = sqrtf(fmaxf(var_x, 0.0f));

        const float delta_norm = sqrtf(s_d2);

        const float total =
              0.5f  * huber1(center_dist)
            +         huber1(fabsf(std_label  - std_pc))
            +         huber1(fabsf(mean_label - mean_pc))
            + 0.01f * huber1(delta_norm)
            +         huber1(fabsf(mean_y_label - mean_y_pc))
            +         huber1(fabsf(std_y_label  - std_y_pc));

        atomicAdd(out, total * (0.4f / (float)B_SZ));
    }
}

extern "C" void kernel_launch(void* const* d_in, const int* in_sizes, int n_in,
                              void* d_out, int out_size, void* d_ws, size_t ws_size,
                              hipStream_t stream) {
    const float* mask_xyz_mean    = (const float*)d_in[0];
    const float* point_cloud      = (const float*)d_in[1];
    const float* x_delta          = (const float*)d_in[2];
    const float* center_label     = (const float*)d_in[3];
    const float* size_residual    = (const float*)d_in[4];
    const float* heading_residual = (const float*)d_in[5];
    const float* mean_sizes       = (const float*)d_in[6];
    const int*   size_class       = (const int*)d_in[7];
    const int*   heading_class    = (const int*)d_in[8];
    float* out = (float*)d_out;

    // d_out is poisoned 0xAA before every timed launch — zero it async (graph-safe)
    hipMemsetAsync(out, 0, sizeof(float), stream);
    loss_kernel<<<GRID, BLOCK, 0, stream>>>(
        mask_xyz_mean, point_cloud, x_delta, center_label, size_residual,
        heading_residual, mean_sizes, size_class, heading_class, out);
}

// Round 3
// 221.601 us; speedup vs baseline: 1.1124x; 1.1124x over previous
//
#include <hip/hip_runtime.h>
#include <math.h>

#define B_SZ 4096
#define N_PTS 2048
#define BLOCK 256

__device__ __forceinline__ float huber1(float a) {
    // a >= 0, delta = 1: 0.5*q*q + (a - q), q = min(a,1)
    float q = fminf(a, 1.0f);
    return 0.5f * q * q + (a - q);
}

// Stage 1: one block per batch element. Contention-free: writes per-element
// total loss to ws[b] (plain store, no atomics — same-address atomicAdd chain
// was the ~80 µs serialization bottleneck in R1/R2).
__global__ __launch_bounds__(BLOCK) void loss_stage1(
    const float* __restrict__ mask_xyz_mean,    // (B,3)
    const float* __restrict__ point_cloud,      // (B,3,N)
    const float* __restrict__ x_delta,          // (B,3,N)
    const float* __restrict__ center_label,     // (B,3)
    const float* __restrict__ size_residual,    // (B,3)
    const float* __restrict__ heading_residual, // (B,)
    const float* __restrict__ mean_sizes,       // (8,3)
    const int*   __restrict__ size_class,       // (B,)
    const int*   __restrict__ heading_class,    // (B,)
    float* __restrict__ ws)                     // (B,) per-element totals
{
    const int b   = blockIdx.x;
    const int tid = threadIdx.x;

    // Block-uniform scalars (same-address broadcast loads)
    const float cx = center_label[b * 3 + 0];
    const float cy = center_label[b * 3 + 1];

    const float vnorm2 = cx * cx + cy * cy;
    const float vnorm  = sqrtf(vnorm2);
    const float pdx = -cy / vnorm;
    const float pdy =  cx / vnorm;

    const size_t base = (size_t)b * 3 * N_PTS;
    const float4* px4 = (const float4*)(point_cloud + base);            // row 0 (x)
    const float4* py4 = (const float4*)(point_cloud + base + N_PTS);    // row 1 (y)
    const float4* pd4 = (const float4*)(x_delta + base);                // 3*N contiguous

    float s_pp = 0.f, s_pp2 = 0.f, s_t = 0.f, s_t2 = 0.f, s_d2 = 0.f;

    // pc rows 0/1: 512 float4 each -> 2 per thread per row
    #pragma unroll
    for (int k = 0; k < N_PTS / 4 / BLOCK; ++k) {
        const int i = tid + k * BLOCK;
        const float4 x4 = px4[i];
        const float4 y4 = py4[i];
        {
            float pp = x4.x * pdx + y4.x * pdy;
            float t  = x4.x * cx  + y4.x * cy;
            s_pp += pp; s_pp2 += pp * pp; s_t += t; s_t2 += t * t;
        }
        {
            float pp = x4.y * pdx + y4.y * pdy;
            float t  = x4.y * cx  + y4.y * cy;
            s_pp += pp; s_pp2 += pp * pp; s_t += t; s_t2 += t * t;
        }
        {
            float pp = x4.z * pdx + y4.z * pdy;
            float t  = x4.z * cx  + y4.z * cy;
            s_pp += pp; s_pp2 += pp * pp; s_t += t; s_t2 += t * t;
        }
        {
            float pp = x4.w * pdx + y4.w * pdy;
            float t  = x4.w * cx  + y4.w * cy;
            s_pp += pp; s_pp2 += pp * pp; s_t += t; s_t2 += t * t;
        }
    }

    // x_delta: 1536 float4 -> 6 per thread
    #pragma unroll
    for (int k = 0; k < 3 * N_PTS / 4 / BLOCK; ++k) {
        const int i = tid + k * BLOCK;
        const float4 d = pd4[i];
        s_d2 += d.x * d.x + d.y * d.y + d.z * d.z + d.w * d.w;
    }

    // wave(64) shuffle reduction
    #pragma unroll
    for (int off = 32; off > 0; off >>= 1) {
        s_pp  += __shfl_down(s_pp,  off, 64);
        s_pp2 += __shfl_down(s_pp2, off, 64);
        s_t   += __shfl_down(s_t,   off, 64);
        s_t2  += __shfl_down(s_t2,  off, 64);
        s_d2  += __shfl_down(s_d2,  off, 64);
    }

    __shared__ float red[BLOCK / 64][5];
    const int wave = tid >> 6;
    const int lane = tid & 63;
    if (lane == 0) {
        red[wave][0] = s_pp;  red[wave][1] = s_pp2;
        red[wave][2] = s_t;   red[wave][3] = s_t2;
        red[wave][4] = s_d2;
    }
    __syncthreads();

    if (tid == 0) {
        #pragma unroll
        for (int w = 1; w < BLOCK / 64; ++w) {
            s_pp  += red[w][0];
            s_pp2 += red[w][1];
            s_t   += red[w][2];
            s_t2  += red[w][3];
            s_d2  += red[w][4];
        }

        // --- label-side scalar math ---
        const float mx = mask_xyz_mean[b * 3 + 0];
        const float my = mask_xyz_mean[b * 3 + 1];
        const float mz = mask_xyz_mean[b * 3 + 2];
        const float cz = center_label[b * 3 + 2];
        const float dxc = mx - cx, dyc = my - cy, dzc = mz - cz;
        const float center_dist = sqrtf(dxc * dxc + dyc * dyc + dzc * dzc);

        const int sc = size_class[b];
        const float l  = mean_sizes[sc * 3 + 0] + size_residual[b * 3 + 0];
        const float w_ = mean_sizes[sc * 3 + 1] + size_residual[b * 3 + 1];
        // h (size z) does not affect the 2D corners used below

        const float theta = heading_residual[b] +
                            (float)heading_class[b] * (float)(M_PI / 12.0);
        const float c = cosf(theta);
        const float s = sinf(theta);
        const float hl = 0.5f * l, hw = 0.5f * w_;

        // bottom corners k=4..7: sx={1,1,-1,-1}, sy={1,-1,-1,1}
        float X[4], Y[4];
        X[0] =  c * hl - s * hw + cx;  Y[0] =  s * hl + c * hw + cy;
        X[1] =  c * hl + s * hw + cx;  Y[1] =  s * hl - c * hw + cy;
        X[2] = -c * hl + s * hw + cx;  Y[2] = -s * hl - c * hw + cy;
        X[3] = -c * hl - s * hw + cx;  Y[3] = -s * hl + c * hw + cy;

        float ppmax = -INFINITY, ppmin = INFINITY;
        float pmax  = -INFINITY, pmin  = INFINITY;
        #pragma unroll
        for (int k = 0; k < 4; ++k) {
            const float pp = X[k] * pdx + Y[k] * pdy;
            const float pj = (X[k] * cx + Y[k] * cy) / vnorm;
            ppmax = fmaxf(ppmax, pp); ppmin = fminf(ppmin, pp);
            pmax  = fmaxf(pmax,  pj); pmin  = fminf(pmin,  pj);
        }
        const float std_y_label  = (ppmax - ppmin) * 0.25f;
        const float mean_y_label = (ppmax + ppmin) * 0.5f;
        const float std_label    = (pmax - pmin) * 0.25f;
        const float mean_label   = (pmax + pmin) * 0.5f;

        // --- point-cloud stats (ddof=1) ---
        const float invN   = 1.0f / (float)N_PTS;
        const float invNm1 = 1.0f / (float)(N_PTS - 1);

        const float mean_y_pc = s_pp * invN;
        const float var_y = (s_pp2 - s_pp * s_pp * invN) * invNm1;
        const float std_y_pc = sqrtf(fmaxf(var_y, 0.0f));

        const float mean_pc = (s_t * invN) / vnorm;
        const float var_x = ((s_t2 - s_t * s_t * invN) * invNm1) / vnorm2;
        const float std_pc = sqrtf(fmaxf(var_x, 0.0f));

        const float delta_norm = sqrtf(s_d2);

        const float total =
              0.5f  * huber1(center_dist)
            +         huber1(fabsf(std_label  - std_pc))
            +         huber1(fabsf(mean_label - mean_pc))
            + 0.01f * huber1(delta_norm)
            +         huber1(fabsf(mean_y_label - mean_y_pc))
            +         huber1(fabsf(std_y_label  - std_y_pc));

        ws[b] = total;   // plain store — no contention
    }
}

// Stage 2: single block reduces the 4096 per-element totals.
__global__ __launch_bounds__(BLOCK) void loss_stage2(
    const float* __restrict__ ws, float* __restrict__ out)
{
    const int tid = threadIdx.x;
    const float4* w4 = (const float4*)ws;   // 1024 float4 -> 4 per thread

    float s = 0.f;
    #pragma unroll
    for (int k = 0; k < B_SZ / 4 / BLOCK; ++k) {
        const float4 v = w4[tid + k * BLOCK];
        s += v.x + v.y + v.z + v.w;
    }

    #pragma unroll
    for (int off = 32; off > 0; off >>= 1)
        s += __shfl_down(s, off, 64);

    __shared__ float red[BLOCK / 64];
    const int wave = tid >> 6;
    const int lane = tid & 63;
    if (lane == 0) red[wave] = s;
    __syncthreads();

    if (tid == 0) {
        #pragma unroll
        for (int w = 1; w < BLOCK / 64; ++w) s += red[w];
        out[0] = s * (0.4f / (float)B_SZ);
    }
}

extern "C" void kernel_launch(void* const* d_in, const int* in_sizes, int n_in,
                              void* d_out, int out_size, void* d_ws, size_t ws_size,
                              hipStream_t stream) {
    const float* mask_xyz_mean    = (const float*)d_in[0];
    const float* point_cloud      = (const float*)d_in[1];
    const float* x_delta          = (const float*)d_in[2];
    const float* center_label     = (const float*)d_in[3];
    const float* size_residual    = (const float*)d_in[4];
    const float* heading_residual = (const float*)d_in[5];
    const float* mean_sizes       = (const float*)d_in[6];
    const int*   size_class       = (const int*)d_in[7];
    const int*   heading_class    = (const int*)d_in[8];
    float* ws  = (float*)d_ws;    // 4096 floats = 16 KB scratch
    float* out = (float*)d_out;

    loss_stage1<<<B_SZ, BLOCK, 0, stream>>>(
        mask_xyz_mean, point_cloud, x_delta, center_label, size_residual,
        heading_residual, mean_sizes, size_class, heading_class, ws);
    loss_stage2<<<1, BLOCK, 0, stream>>>(ws, out);
}